// Round 2
// baseline (31.030 us; speedup 1.0000x reference)
//
#include <hip/hip_runtime.h>

// YOLO loss forward, MI355X. Memory-bound streaming reduction.
// pred/target: (2048, 14, 14, 30) fp32, channel-innermost contiguous.
// R2: direct per-thread float2 global loads (cell = 120 B, always 8B-aligned);
//     no LDS staging, no barrier, no LDS occupancy cap.

constexpr int N_IMG = 2048;
constexpr int NC    = 30;
constexpr int CELLS = N_IMG * 14 * 14;   // 401408
constexpr int BLOCK = 256;
constexpr int GRID  = CELLS / BLOCK;     // 1568 (exact)
constexpr float INV14 = 1.0f / 14.0f;

__global__ __launch_bounds__(BLOCK)
void yolo_cell(const float* __restrict__ pred,
               const float* __restrict__ targ,
               float* __restrict__ partial)
{
    const int tid  = threadIdx.x;
    const int cell = blockIdx.x * BLOCK + tid;

    // ---- direct loads: 15 x float2 per array (8B-aligned for every cell) ----
    float pv[NC], tv[NC];
    {
        const float2* p2 = reinterpret_cast<const float2*>(pred + (size_t)cell * NC);
        const float2* t2 = reinterpret_cast<const float2*>(targ + (size_t)cell * NC);
        #pragma unroll
        for (int i = 0; i < NC / 2; ++i) {
            float2 a = p2[i]; pv[2*i] = a.x; pv[2*i+1] = a.y;
            float2 b = t2[i]; tv[2*i] = b.x; tv[2*i+1] = b.y;
        }
    }

    const float coo = (tv[4] > 0.0f) ? 1.0f : 0.0f;

    // target box 0 -> xyxy
    const float txc = tv[0] * INV14, tyc = tv[1] * INV14;
    const float tx1 = txc - 0.5f * tv[2], ty1 = tyc - 0.5f * tv[3];
    const float tx2 = txc + 0.5f * tv[2], ty2 = tyc + 0.5f * tv[3];
    const float t_area = (tx2 - tx1) * (ty2 - ty1);

    float iou0, iou1;
    {
        const float xc = pv[0] * INV14, yc = pv[1] * INV14;
        const float x1 = xc - 0.5f * pv[2], y1 = yc - 0.5f * pv[3];
        const float x2 = xc + 0.5f * pv[2], y2 = yc + 0.5f * pv[3];
        const float a1 = (x2 - x1) * (y2 - y1);
        const float wx = fmaxf(fminf(x2, tx2) - fmaxf(x1, tx1), 0.0f);
        const float wy = fmaxf(fminf(y2, ty2) - fmaxf(y1, ty1), 0.0f);
        const float inter = wx * wy;
        iou0 = inter / (a1 + t_area - inter);
    }
    {
        const float xc = pv[5] * INV14, yc = pv[6] * INV14;
        const float x1 = xc - 0.5f * pv[7], y1 = yc - 0.5f * pv[8];
        const float x2 = xc + 0.5f * pv[7], y2 = yc + 0.5f * pv[8];
        const float a1 = (x2 - x1) * (y2 - y1);
        const float wx = fmaxf(fminf(x2, tx2) - fmaxf(x1, tx1), 0.0f);
        const float wy = fmaxf(fminf(y2, ty2) - fmaxf(y1, ty1), 0.0f);
        const float inter = wx * wy;
        iou1 = inter / (a1 + t_area - inter);
    }

    // jnp.argmax first-max tie-break: r=1 only if iou1 strictly greater.
    // Static-index selects (v_cndmask), not runtime array indexing (rule #20).
    const bool sel = iou1 > iou0;
    const float rp0 = sel ? pv[5] : pv[0];
    const float rp1 = sel ? pv[6] : pv[1];
    const float rp2 = sel ? pv[7] : pv[2];
    const float rp3 = sel ? pv[8] : pv[3];
    const float rp4 = sel ? pv[9] : pv[4];
    const float rt0 = sel ? tv[5] : tv[0];
    const float rt1 = sel ? tv[6] : tv[1];
    const float rt2 = sel ? tv[7] : tv[2];
    const float rt3 = sel ? tv[8] : tv[3];
    const float nrp4 = sel ? pv[4] : pv[9];

    const float d0 = rp0 - rt0, d1 = rp1 - rt1;
    const float d2 = sqrtf(rp2) - sqrtf(rt2);
    const float d3 = sqrtf(rp3) - sqrtf(rt3);
    const float loc     = d0*d0 + d1*d1 + d2*d2 + d3*d3;
    const float contain = rp4 * rp4;
    const float notc    = nrp4 * nrp4;
    const float e4 = pv[4] - tv[4], e9 = pv[9] - tv[9];
    const float noobj = e4*e4 + e9*e9;
    float cls = 0.0f;
    #pragma unroll
    for (int c = 10; c < NC; ++c) { const float d = pv[c] - tv[c]; cls += d*d; }

    float cellv = coo * (5.0f * loc + 2.0f * contain + notc + cls)
                + (1.0f - coo) * (0.5f * noobj);

    // ---- block reduction (wave64 shuffle + LDS) ----
    __shared__ float wsum[BLOCK / 64];
    #pragma unroll
    for (int o = 32; o > 0; o >>= 1) cellv += __shfl_down(cellv, o, 64);
    if ((tid & 63) == 0) wsum[tid >> 6] = cellv;
    __syncthreads();
    if (tid == 0)
        partial[blockIdx.x] = wsum[0] + wsum[1] + wsum[2] + wsum[3];
}

__global__ __launch_bounds__(256)
void yolo_final(const float* __restrict__ partial, float* __restrict__ out)
{
    const int tid = threadIdx.x;
    double s = 0.0;
    for (int i = tid; i < GRID; i += 256) s += (double)partial[i];
    #pragma unroll
    for (int o = 32; o > 0; o >>= 1) s += __shfl_down(s, o, 64);
    __shared__ double w[4];
    if ((tid & 63) == 0) w[tid >> 6] = s;
    __syncthreads();
    if (tid == 0) out[0] = (float)((w[0] + w[1] + w[2] + w[3]) / (double)N_IMG);
}

extern "C" void kernel_launch(void* const* d_in, const int* in_sizes, int n_in,
                              void* d_out, int out_size, void* d_ws, size_t ws_size,
                              hipStream_t stream)
{
    const float* pred = (const float*)d_in[0];
    const float* targ = (const float*)d_in[1];
    float* out        = (float*)d_out;
    float* partial    = (float*)d_ws;   // GRID floats = 6272 B

    yolo_cell<<<GRID, BLOCK, 0, stream>>>(pred, targ, partial);
    yolo_final<<<1, 256, 0, stream>>>(partial, out);
}

// Round 3
// 24.199 us; speedup vs baseline: 1.2823x; 1.2823x over previous
//
#include <hip/hip_runtime.h>

// YOLO loss forward, MI355X. Memory-bound streaming reduction.
// R3: persistent 224-block grid, double-buffered LDS, global_load_lds(16B)
//     direct-to-LDS staging, 2-phase prefetch pipeline, divide-free argmax.

constexpr int N_IMG  = 2048;
constexpr int NC     = 30;
constexpr int CELLS  = N_IMG * 14 * 14;        // 401408
constexpr int BLOCK  = 256;
constexpr int CPB    = 256;                    // cells per chunk
constexpr int NCHUNK = 7;
constexpr int GRID   = CELLS / (CPB * NCHUNK); // 224 (exact)
constexpr float INV14 = 1.0f / 14.0f;

__device__ __forceinline__ void gload16(const void* g, void* l) {
    __builtin_amdgcn_global_load_lds(
        (const __attribute__((address_space(1))) void*)g,
        (__attribute__((address_space(3))) void*)l, 16, 0, 0);
}

__device__ __forceinline__ float cell_loss(const float* __restrict__ cp,
                                           const float* __restrict__ ct)
{
    float pv[NC], tv[NC];
    const float2* p2 = reinterpret_cast<const float2*>(cp);  // 8B-aligned (cell*120B)
    const float2* t2 = reinterpret_cast<const float2*>(ct);
    #pragma unroll
    for (int i = 0; i < NC / 2; ++i) {
        float2 a = p2[i]; pv[2*i] = a.x; pv[2*i+1] = a.y;
        float2 b = t2[i]; tv[2*i] = b.x; tv[2*i+1] = b.y;
    }

    const float coo = (tv[4] > 0.0f) ? 1.0f : 0.0f;

    const float txc = tv[0] * INV14, tyc = tv[1] * INV14;
    const float tx1 = txc - 0.5f * tv[2], ty1 = tyc - 0.5f * tv[3];
    const float tx2 = txc + 0.5f * tv[2], ty2 = tyc + 0.5f * tv[3];
    const float t_area = (tx2 - tx1) * (ty2 - ty1);

    // box 0
    float i0, u0;
    {
        const float xc = pv[0] * INV14, yc = pv[1] * INV14;
        const float x1 = xc - 0.5f * pv[2], y1 = yc - 0.5f * pv[3];
        const float x2 = xc + 0.5f * pv[2], y2 = yc + 0.5f * pv[3];
        const float a1 = (x2 - x1) * (y2 - y1);
        const float wx = fmaxf(fminf(x2, tx2) - fmaxf(x1, tx1), 0.0f);
        const float wy = fmaxf(fminf(y2, ty2) - fmaxf(y1, ty1), 0.0f);
        i0 = wx * wy;
        u0 = a1 + t_area - i0;          // union area > 0 (w,h >= 0.05)
    }
    // box 1
    float i1, u1;
    {
        const float xc = pv[5] * INV14, yc = pv[6] * INV14;
        const float x1 = xc - 0.5f * pv[7], y1 = yc - 0.5f * pv[8];
        const float x2 = xc + 0.5f * pv[7], y2 = yc + 0.5f * pv[8];
        const float a1 = (x2 - x1) * (y2 - y1);
        const float wx = fmaxf(fminf(x2, tx2) - fmaxf(x1, tx1), 0.0f);
        const float wy = fmaxf(fminf(y2, ty2) - fmaxf(y1, ty1), 0.0f);
        i1 = wx * wy;
        u1 = a1 + t_area - i1;
    }

    // argmax first-max tie-break, divide-free: iou1 > iou0  <=>  i1*u0 > i0*u1
    const bool sel = (i1 * u0) > (i0 * u1);
    const float rp0 = sel ? pv[5] : pv[0];
    const float rp1 = sel ? pv[6] : pv[1];
    const float rp2 = sel ? pv[7] : pv[2];
    const float rp3 = sel ? pv[8] : pv[3];
    const float rp4 = sel ? pv[9] : pv[4];
    const float rt0 = sel ? tv[5] : tv[0];
    const float rt1 = sel ? tv[6] : tv[1];
    const float rt2 = sel ? tv[7] : tv[2];
    const float rt3 = sel ? tv[8] : tv[3];
    const float nrp4 = sel ? pv[4] : pv[9];

    const float d0 = rp0 - rt0, d1 = rp1 - rt1;
    const float d2 = sqrtf(rp2) - sqrtf(rt2);
    const float d3 = sqrtf(rp3) - sqrtf(rt3);
    const float loc     = d0*d0 + d1*d1 + d2*d2 + d3*d3;
    const float contain = rp4 * rp4;
    const float notc    = nrp4 * nrp4;
    const float e4 = pv[4] - tv[4], e9 = pv[9] - tv[9];
    const float noobj = e4*e4 + e9*e9;
    float cls = 0.0f;
    #pragma unroll
    for (int c = 10; c < NC; ++c) { const float d = pv[c] - tv[c]; cls += d*d; }

    return coo * (5.0f * loc + 2.0f * contain + notc + cls)
         + (1.0f - coo) * (0.5f * noobj);
}

__global__ __launch_bounds__(BLOCK)
void yolo_main(const float* __restrict__ pred,
               const float* __restrict__ targ,
               float* __restrict__ partial)
{
    __shared__ float sp[2][CPB * NC];   // 2 x 30720 B
    __shared__ float st[2][CPB * NC];   // 2 x 30720 B

    const int tid = threadIdx.x;
    const int bid = blockIdx.x;

    // stage chunk c into buffer buf: 1920 float4 per array, linear LDS dest
    // (global_load_lds: wave-uniform base + lane*16 -- layout is exactly linear)
    auto stage = [&](int buf, int c) {
        const size_t fbase = (size_t)(bid * NCHUNK + c) * (size_t)(CPB * NC);
        const float4* gp = reinterpret_cast<const float4*>(pred + fbase);
        const float4* gt = reinterpret_cast<const float4*>(targ + fbase);
        float4* lp = reinterpret_cast<float4*>(sp[buf]);
        float4* lt = reinterpret_cast<float4*>(st[buf]);
        #pragma unroll
        for (int i = 0; i < 7; ++i)
            gload16(gp + i * BLOCK + tid, lp + i * BLOCK + tid);
        if (tid < 128)                         // waves 0,1 fully active (wave-uniform)
            gload16(gp + 7 * BLOCK + tid, lp + 7 * BLOCK + tid);
        #pragma unroll
        for (int i = 0; i < 7; ++i)
            gload16(gt + i * BLOCK + tid, lt + i * BLOCK + tid);
        if (tid < 128)
            gload16(gt + 7 * BLOCK + tid, lt + 7 * BLOCK + tid);
    };

    stage(0, 0);
    __syncthreads();                    // compiler drains vmcnt(0) before barrier

    float acc = 0.0f;
    for (int c = 0; c < NCHUNK; ++c) {
        const int cur = c & 1;
        if (c + 1 < NCHUNK) stage(cur ^ 1, c + 1);   // issue BEFORE compute
        acc += cell_loss(&sp[cur][tid * NC], &st[cur][tid * NC]);
        __syncthreads();   // drain: next buffer ready; overwrite-safe for c+2
    }

    // block reduction
    __shared__ float wsum[BLOCK / 64];
    #pragma unroll
    for (int o = 32; o > 0; o >>= 1) acc += __shfl_down(acc, o, 64);
    if ((tid & 63) == 0) wsum[tid >> 6] = acc;
    __syncthreads();
    if (tid == 0)
        partial[bid] = wsum[0] + wsum[1] + wsum[2] + wsum[3];
}

__global__ __launch_bounds__(64)
void yolo_final(const float* __restrict__ partial, float* __restrict__ out)
{
    const int tid = threadIdx.x;
    double s = 0.0;
    for (int i = tid; i < GRID; i += 64) s += (double)partial[i];
    #pragma unroll
    for (int o = 32; o > 0; o >>= 1) s += __shfl_down(s, o, 64);
    if (tid == 0) out[0] = (float)(s / (double)N_IMG);
}

extern "C" void kernel_launch(void* const* d_in, const int* in_sizes, int n_in,
                              void* d_out, int out_size, void* d_ws, size_t ws_size,
                              hipStream_t stream)
{
    const float* pred = (const float*)d_in[0];
    const float* targ = (const float*)d_in[1];
    float* out        = (float*)d_out;
    float* partial    = (float*)d_ws;   // GRID floats = 896 B

    yolo_main<<<GRID, BLOCK, 0, stream>>>(pred, targ, partial);
    yolo_final<<<1, 64, 0, stream>>>(partial, out);
}